// Round 11
// baseline (405.454 us; speedup 1.0000x reference)
//
#include <hip/hip_runtime.h>
#include <math.h>

#define D_MODEL 1024
#define D_INNER 2048
#define D_STATE 16
#define D_CONV  4
#define DT_RANK 64
#define B_SZ    2
#define SEQ     2048
#define NTOK    (B_SZ*SEQ)            // 4096
#define DBL_N   (DT_RANK + 2*D_STATE) // 96
#define CHUNK   64
#define NCHUNK  (SEQ/CHUNK)           // 32

typedef __attribute__((ext_vector_type(8))) short short8;
typedef __attribute__((ext_vector_type(4))) float f32x4;

__device__ __forceinline__ unsigned short f2bf(float f) {
    union { float f; unsigned int u; } v; v.f = f;
    unsigned int r = v.u + 0x7fff + ((v.u >> 16) & 1);   // RNE
    return (unsigned short)(r >> 16);
}
__device__ __forceinline__ float bf2f(unsigned short u) {
    union { unsigned int u; float f; } v; v.u = ((unsigned int)u) << 16;
    return v.f;
}

// ---------------- RMSNorm: one block per token, bf16 output ----------------
__global__ __launch_bounds__(256) void rmsnorm_kernel(
    const float* __restrict__ h, const float* __restrict__ w, unsigned short* __restrict__ out)
{
    int tok = blockIdx.x;
    const float4* row = (const float4*)(h + (size_t)tok * D_MODEL);
    float4 v = row[threadIdx.x];
    float ss = v.x*v.x + v.y*v.y + v.z*v.z + v.w*v.w;
    #pragma unroll
    for (int off = 32; off >= 1; off >>= 1) ss += __shfl_down(ss, off, 64);
    __shared__ float red[4];
    int wave = threadIdx.x >> 6, lane = threadIdx.x & 63;
    if (lane == 0) red[wave] = ss;
    __syncthreads();
    float tot = red[0] + red[1] + red[2] + red[3];
    float scale = rsqrtf(tot * (1.0f / D_MODEL) + 1e-5f);
    float4 wv = ((const float4*)w)[threadIdx.x];
    ushort4 o;
    o.x = f2bf(v.x * scale * wv.x);
    o.y = f2bf(v.y * scale * wv.y);
    o.z = f2bf(v.z * scale * wv.z);
    o.w = f2bf(v.w * scale * wv.w);
    ((ushort4*)(out + (size_t)tok * D_MODEL))[threadIdx.x] = o;
}

// ---------------- fused fp32 -> bf16 cast for 4 weight matrices ----------------
__global__ __launch_bounds__(256) void cast4_kernel(
    const float4* __restrict__ s0, ushort4* __restrict__ d0, int n0,
    const float4* __restrict__ s1, ushort4* __restrict__ d1, int n1,
    const float4* __restrict__ s2, ushort4* __restrict__ d2, int n2,
    const float4* __restrict__ s3, ushort4* __restrict__ d3, int n3)
{
    int i = blockIdx.x * 256 + threadIdx.x;
    const float4* s; ushort4* d;
    if (i < n0) { s = s0; d = d0; }
    else if ((i -= n0) < n1) { s = s1; d = d1; }
    else if ((i -= n1) < n2) { s = s2; d = d2; }
    else if ((i -= n2) < n3) { s = s3; d = d3; }
    else return;
    float4 v = s[i];
    ushort4 o; o.x = f2bf(v.x); o.y = f2bf(v.y); o.z = f2bf(v.z); o.w = f2bf(v.w);
    d[i] = o;
}

// ---------------- DIRECT bf16 MFMA GEMM: no LDS, no barriers ----------------
// Fragments loaded straight from global (line-coalesced: 16 rows x 64B per instr,
// served by L2/L3). 128x128 block tile, 64x64 wave tile, transposed accumulator.
__global__ __launch_bounds__(256) void mfma_gemm_direct_kernel(
    const unsigned short* __restrict__ A, int lda,
    const unsigned short* __restrict__ W, int ldw,
    unsigned short* __restrict__ Cbf, int ldcbf,
    int K)
{
    const int bm = blockIdx.y * 128;
    const int bn = blockIdx.x * 128;
    const int lane = threadIdx.x & 63;
    const int wave = threadIdx.x >> 6;
    const int wm = (wave >> 1) * 64;
    const int wn = (wave & 1) * 64;
    const int frow = lane & 15;
    const int quad = lane >> 4;

    const unsigned short* Abase = A + (size_t)(bm + wm + frow) * lda + quad * 8;
    const unsigned short* Wbase = W + (size_t)(bn + wn + frow) * ldw + quad * 8;

    f32x4 acc[4][4];
    #pragma unroll
    for (int i = 0; i < 4; ++i)
        #pragma unroll
        for (int j = 0; j < 4; ++j)
            acc[i][j] = (f32x4){0.f, 0.f, 0.f, 0.f};

    #pragma unroll 2
    for (int k0 = 0; k0 < K; k0 += 32) {
        short8 af[4], bf[4];
        #pragma unroll
        for (int i = 0; i < 4; ++i)
            af[i] = *(const short8*)(Abase + (size_t)(i * 16) * lda + k0);
        #pragma unroll
        for (int j = 0; j < 4; ++j)
            bf[j] = *(const short8*)(Wbase + (size_t)(j * 16) * ldw + k0);
        #pragma unroll
        for (int i = 0; i < 4; ++i)
            #pragma unroll
            for (int j = 0; j < 4; ++j)
                acc[i][j] = __builtin_amdgcn_mfma_f32_16x16x32_bf16(
                    bf[j], af[i], acc[i][j], 0, 0, 0);
    }

    // epilogue: lane -> row = bm+wm+16i+frow, cols = bn+wn+16j+quad*4 + {0..3}
    #pragma unroll
    for (int i = 0; i < 4; ++i) {
        int row = bm + wm + i * 16 + frow;
        #pragma unroll
        for (int j = 0; j < 4; ++j) {
            int col = bn + wn + j * 16 + quad * 4;
            f32x4 v = acc[i][j];
            ushort4 o = {f2bf(v[0]), f2bf(v[1]), f2bf(v[2]), f2bf(v[3])};
            *(ushort4*)&Cbf[(size_t)row * ldcbf + col] = o;
        }
    }
}

// ---------------- bf16 MFMA GEMM (128x128, LDS), transposed accumulator ----------------
__global__ __launch_bounds__(256) void mfma_gemm_kernel(
    const unsigned short* __restrict__ A, int lda,
    const unsigned short* __restrict__ W, int ldw,
    float* __restrict__ C, int ldc,
    unsigned short* __restrict__ Cbf, int ldcbf,
    int kLen, int Nmax,
    const float* __restrict__ add, int ldadd,
    size_t segStride)
{
    __shared__ __align__(16) unsigned short As[128 * 32];
    __shared__ __align__(16) unsigned short Bs[128 * 32];
    const int bm = blockIdx.y * 128;
    const int bn = blockIdx.x * 128;
    const int kBeg = blockIdx.z * kLen;
    const int tid = threadIdx.x;
    const int lane = tid & 63;
    const int wave = tid >> 6;
    const int wm = (wave >> 1) * 64;
    const int wn = (wave & 1) * 64;
    const int frow = lane & 15;
    const int quad = lane >> 4;

    if (C) C += blockIdx.z * segStride;

    f32x4 acc[4][4];
    #pragma unroll
    for (int i = 0; i < 4; ++i)
        #pragma unroll
        for (int j = 0; j < 4; ++j)
            acc[i][j] = (f32x4){0.f, 0.f, 0.f, 0.f};

    for (int k0 = kBeg; k0 < kBeg + kLen; k0 += 32) {
        __syncthreads();
        #pragma unroll
        for (int i = 0; i < 2; ++i) {
            int q = (wave * 2 + i) * 64 + lane;
            int r = q >> 2, cl = q & 3;
            const unsigned short* ga = A + (size_t)(bm + r) * lda + k0 + cl * 8;
            const unsigned short* gb = W + (size_t)(bn + r) * ldw + k0 + cl * 8;
            __builtin_amdgcn_global_load_lds(
                (const __attribute__((address_space(1))) void*)ga,
                (__attribute__((address_space(3))) void*)(As + (wave * 2 + i) * 512),
                16, 0, 0);
            __builtin_amdgcn_global_load_lds(
                (const __attribute__((address_space(1))) void*)gb,
                (__attribute__((address_space(3))) void*)(Bs + (wave * 2 + i) * 512),
                16, 0, 0);
        }
        __syncthreads();
        short8 af[4], bf[4];
        #pragma unroll
        for (int i = 0; i < 4; ++i)
            af[i] = *(const short8*)&As[(wm + i * 16 + frow) * 32 + quad * 8];
        #pragma unroll
        for (int j = 0; j < 4; ++j)
            bf[j] = *(const short8*)&Bs[(wn + j * 16 + frow) * 32 + quad * 8];
        #pragma unroll
        for (int i = 0; i < 4; ++i)
            #pragma unroll
            for (int j = 0; j < 4; ++j)
                acc[i][j] = __builtin_amdgcn_mfma_f32_16x16x32_bf16(
                    bf[j], af[i], acc[i][j], 0, 0, 0);
    }

    #pragma unroll
    for (int i = 0; i < 4; ++i) {
        int row = bm + wm + i * 16 + frow;
        #pragma unroll
        for (int j = 0; j < 4; ++j) {
            int col = bn + wn + j * 16 + quad * 4;
            if (col < Nmax) {
                f32x4 v = acc[i][j];
                if (add) {
                    float4 av = *(const float4*)&add[(size_t)row * ldadd + col];
                    v[0] += av.x; v[1] += av.y; v[2] += av.z; v[3] += av.w;
                }
                if (C) {
                    float4 o = {v[0], v[1], v[2], v[3]};
                    *(float4*)&C[(size_t)row * ldc + col] = o;
                }
                if (Cbf) {
                    ushort4 o = {f2bf(v[0]), f2bf(v[1]), f2bf(v[2]), f2bf(v[3])};
                    *(ushort4*)&Cbf[(size_t)row * ldcbf + col] = o;
                }
            }
        }
    }
}

// ---------------- dt_proj: 64x64-tile MFMA GEMM + bias + fast softplus ----------------
__global__ __launch_bounds__(256) void dtproj_kernel(
    const unsigned short* __restrict__ A,
    const unsigned short* __restrict__ W,
    const float* __restrict__ bias,
    float* __restrict__ C)
{
    __shared__ __align__(16) unsigned short As[64 * 32];
    __shared__ __align__(16) unsigned short Bs[64 * 32];
    const int bm = blockIdx.y * 64;
    const int bn = blockIdx.x * 64;
    const int tid = threadIdx.x;
    const int lane = tid & 63;
    const int wave = tid >> 6;
    const int frow = lane & 15;
    const int quad = lane >> 4;

    f32x4 acc[4];
    #pragma unroll
    for (int i = 0; i < 4; ++i) acc[i] = (f32x4){0.f, 0.f, 0.f, 0.f};

    #pragma unroll
    for (int k0 = 0; k0 < DT_RANK; k0 += 32) {
        __syncthreads();
        {
            int r = tid >> 2, cl = tid & 3;
            const unsigned short* ga = A + (size_t)(bm + r) * DT_RANK + k0 + cl * 8;
            const unsigned short* gb = W + (size_t)(bn + r) * DT_RANK + k0 + cl * 8;
            __builtin_amdgcn_global_load_lds(
                (const __attribute__((address_space(1))) void*)ga,
                (__attribute__((address_space(3))) void*)(As + wave * 512),
                16, 0, 0);
            __builtin_amdgcn_global_load_lds(
                (const __attribute__((address_space(1))) void*)gb,
                (__attribute__((address_space(3))) void*)(Bs + wave * 512),
                16, 0, 0);
        }
        __syncthreads();
        short8 bf = *(const short8*)&Bs[(wave * 16 + frow) * 32 + quad * 8];
        #pragma unroll
        for (int i = 0; i < 4; ++i) {
            short8 af = *(const short8*)&As[(i * 16 + frow) * 32 + quad * 8];
            acc[i] = __builtin_amdgcn_mfma_f32_16x16x32_bf16(bf, af, acc[i], 0, 0, 0);
        }
    }

    const int col = bn + wave * 16 + quad * 4;
    float4 bv = *(const float4*)&bias[col];
    #pragma unroll
    for (int i = 0; i < 4; ++i) {
        int row = bm + i * 16 + frow;
        f32x4 v = acc[i];
        v[0] += bv.x; v[1] += bv.y; v[2] += bv.z; v[3] += bv.w;
        #pragma unroll
        for (int r = 0; r < 4; ++r)
            v[r] = (v[r] > 15.0f) ? v[r] : __logf(1.0f + __expf(v[r]));
        float4 o = {v[0], v[1], v[2], v[3]};
        *(float4*)&C[(size_t)row * D_INNER + col] = o;
    }
}

// ---------------- x_proj split-K reduce + dt_r bf16 extract ----------------
__global__ __launch_bounds__(256) void reduce_xproj_kernel(
    const float* __restrict__ part, float* __restrict__ dbl,
    unsigned short* __restrict__ dtr)
{
    const int N = NTOK * DBL_N;
    int idx = blockIdx.x * 256 + threadIdx.x;
    if (idx >= N) return;
    float s = part[idx] + part[idx + N] + part[idx + 2 * N] + part[idx + 3 * N];
    dbl[idx] = s;
    unsigned int col = (unsigned int)idx % DBL_N;
    if (col < DT_RANK) {
        unsigned int tok = (unsigned int)idx / DBL_N;
        dtr[(size_t)tok * DT_RANK + col] = f2bf(s);
    }
}

// ---------------- Causal depthwise conv (k=4) + SiLU, bf16 in/out ----------------
__global__ __launch_bounds__(256) void conv_silu_kernel(
    const unsigned short* __restrict__ xz, const float* __restrict__ cw,
    const float* __restrict__ cb, unsigned short* __restrict__ out_bf)
{
    int idx = blockIdx.x * 256 + threadIdx.x;   // over NTOK*D_INNER
    int d = idx & (D_INNER - 1);
    int t = (idx >> 11) & (SEQ - 1);
    int b = idx >> 22;
    const unsigned short* xcol = xz + (size_t)b * SEQ * (2 * D_INNER) + d;
    float w0 = cw[d * 4 + 0], w1 = cw[d * 4 + 1], w2 = cw[d * 4 + 2], w3 = cw[d * 4 + 3];
    float acc = cb[d];
    if (t >= 3) acc = fmaf(bf2f(xcol[(size_t)(t - 3) * (2 * D_INNER)]), w0, acc);
    if (t >= 2) acc = fmaf(bf2f(xcol[(size_t)(t - 2) * (2 * D_INNER)]), w1, acc);
    if (t >= 1) acc = fmaf(bf2f(xcol[(size_t)(t - 1) * (2 * D_INNER)]), w2, acc);
    acc = fmaf(bf2f(xcol[(size_t)t * (2 * D_INNER)]), w3, acc);
    float sig = 1.0f / (1.0f + __expf(-acc));
    out_bf[(size_t)(b * SEQ + t) * D_INNER + d] = f2bf(acc * sig);
}

// ---------------- Scan phase 1: per-chunk summaries, one thread per d ----------------
__global__ __launch_bounds__(256) void scan_phase1_kernel(
    const float* __restrict__ dtb, const unsigned short* __restrict__ xconv,
    const float* __restrict__ dbl, const float* __restrict__ A_log,
    float* __restrict__ sum_a, float* __restrict__ sum_h)
{
    const int d = blockIdx.y * 256 + threadIdx.x;
    const int c = blockIdx.x;
    const int b = blockIdx.z;
    const int t0 = c * CHUNK;

    float An[D_STATE];
    bool fast = true;
    #pragma unroll
    for (int n = 0; n < D_STATE; ++n) {
        An[n] = -__expf(A_log[d * D_STATE + n]);
        fast = fast && (fabsf(An[n] + (float)(n + 1)) < 2e-3f);
    }
    const float* dt_p = dtb + ((size_t)b * SEQ + t0) * D_INNER + d;
    const unsigned short* x_p = xconv + ((size_t)b * SEQ + t0) * D_INNER + d;
    const float* Brow = dbl + ((size_t)b * SEQ + t0) * DBL_N + DT_RANK;   // wave-uniform

    float h[D_STATE];
    #pragma unroll
    for (int n = 0; n < D_STATE; ++n) h[n] = 0.f;
    float sumdt = 0.f;

    if (fast) {
        for (int t = 0; t < CHUNK; ++t) {
            float dt = dt_p[(size_t)t * D_INNER];
            float xv = bf2f(x_p[(size_t)t * D_INNER]);
            const float4* B4 = (const float4*)(Brow + (size_t)t * DBL_N);
            float4 b0 = B4[0], b1 = B4[1], b2 = B4[2], b3 = B4[3];
            float Bv[16] = {b0.x,b0.y,b0.z,b0.w, b1.x,b1.y,b1.z,b1.w,
                            b2.x,b2.y,b2.z,b2.w, b3.x,b3.y,b3.z,b3.w};
            sumdt += dt;
            float e1 = __expf(-dt);
            float dtx = dt * xv;
            float ea = 1.f;
            #pragma unroll
            for (int n = 0; n < D_STATE; ++n) {
                ea *= e1;
                h[n] = fmaf(h[n], ea, dtx * Bv[n]);
            }
        }
    } else {
        for (int t = 0; t < CHUNK; ++t) {
            float dt = dt_p[(size_t)t * D_INNER];
            float xv = bf2f(x_p[(size_t)t * D_INNER]);
            const float4* B4 = (const float4*)(Brow + (size_t)t * DBL_N);
            float4 b0 = B4[0], b1 = B4[1], b2 = B4[2], b3 = B4[3];
            float Bv[16] = {b0.x,b0.y,b0.z,b0.w, b1.x,b1.y,b1.z,b1.w,
                            b2.x,b2.y,b2.z,b2.w, b3.x,b3.y,b3.z,b3.w};
            sumdt += dt;
            float dtx = dt * xv;
            #pragma unroll
            for (int n = 0; n < D_STATE; ++n) {
                float ea = __expf(dt * An[n]);
                h[n] = fmaf(h[n], ea, dtx * Bv[n]);
            }
        }
    }

    float a[D_STATE];
    if (fast) {
        float E = __expf(-sumdt);
        float ea = 1.f;
        #pragma unroll
        for (int n = 0; n < D_STATE; ++n) { ea *= E; a[n] = ea; }
    } else {
        #pragma unroll
        for (int n = 0; n < D_STATE; ++n) a[n] = __expf(An[n] * sumdt);
    }
    size_t base = (((size_t)b * D_INNER + d) * NCHUNK + c) * D_STATE;
    #pragma unroll
    for (int i = 0; i < 4; ++i) {
        ((float4*)(sum_a + base))[i] = (float4){a[4*i], a[4*i+1], a[4*i+2], a[4*i+3]};
        ((float4*)(sum_h + base))[i] = (float4){h[4*i], h[4*i+1], h[4*i+2], h[4*i+3]};
    }
}

// ---------------- Scan phase 2: inter-chunk carry (in-place over sum_h) ----------------
__global__ __launch_bounds__(256) void scan_carry_kernel(
    const float* __restrict__ sum_a, float* __restrict__ sum_h)
{
    size_t g = (size_t)blockIdx.x * 256 + threadIdx.x;   // (b,d,n): 65536 groups
    size_t bd = g >> 4;
    int n = (int)(g & 15);
    size_t base = bd * NCHUNK * D_STATE + n;
    float hh = 0.f;
    for (int c = 0; c < NCHUNK; ++c) {
        size_t idx = base + (size_t)c * D_STATE;
        float a = sum_a[idx];
        float hp = sum_h[idx];
        sum_h[idx] = hh;
        hh = fmaf(hh, a, hp);
    }
}

// ---------------- Scan phase 3: re-scan with carry, emit y (bf16) ----------------
__global__ __launch_bounds__(256) void scan_phase3_kernel(
    const float* __restrict__ dtb, const unsigned short* __restrict__ xconv,
    const unsigned short* __restrict__ xz, const float* __restrict__ dbl,
    const float* __restrict__ A_log, const float* __restrict__ Dvec,
    const float* __restrict__ hinit, unsigned short* __restrict__ y)
{
    const int d = blockIdx.y * 256 + threadIdx.x;
    const int c = blockIdx.x;
    const int b = blockIdx.z;
    const int t0 = c * CHUNK;

    float An[D_STATE];
    bool fast = true;
    #pragma unroll
    for (int n = 0; n < D_STATE; ++n) {
        An[n] = -__expf(A_log[d * D_STATE + n]);
        fast = fast && (fabsf(An[n] + (float)(n + 1)) < 2e-3f);
    }
    const float Dd = Dvec[d];
    const float* dt_p = dtb + ((size_t)b * SEQ + t0) * D_INNER + d;
    const unsigned short* x_p = xconv + ((size_t)b * SEQ + t0) * D_INNER + d;
    const unsigned short* z_p = xz + ((size_t)b * SEQ + t0) * (2 * D_INNER) + D_INNER + d;
    const float* Brow = dbl + ((size_t)b * SEQ + t0) * DBL_N + DT_RANK;
    unsigned short* y_p = y + ((size_t)b * SEQ + t0) * D_INNER + d;

    size_t base = (((size_t)b * D_INNER + d) * NCHUNK + c) * D_STATE;
    float h[D_STATE];
    #pragma unroll
    for (int i = 0; i < 4; ++i) {
        float4 hv = ((const float4*)(hinit + base))[i];
        h[4*i] = hv.x; h[4*i+1] = hv.y; h[4*i+2] = hv.z; h[4*i+3] = hv.w;
    }

    if (fast) {
        for (int t = 0; t < CHUNK; ++t) {
            float dt = dt_p[(size_t)t * D_INNER];
            float xv = bf2f(x_p[(size_t)t * D_INNER]);
            const float4* B4 = (const float4*)(Brow + (size_t)t * DBL_N);
            float4 b0 = B4[0], b1 = B4[1], b2 = B4[2], b3 = B4[3];
            float4 c0 = B4[4], c1 = B4[5], c2 = B4[6], c3 = B4[7];
            float Bv[16] = {b0.x,b0.y,b0.z,b0.w, b1.x,b1.y,b1.z,b1.w,
                            b2.x,b2.y,b2.z,b2.w, b3.x,b3.y,b3.z,b3.w};
            float Cv[16] = {c0.x,c0.y,c0.z,c0.w, c1.x,c1.y,c1.z,c1.w,
                            c2.x,c2.y,c2.z,c2.w, c3.x,c3.y,c3.z,c3.w};
            float e1 = __expf(-dt);
            float dtx = dt * xv;
            float ea = 1.f, yy = 0.f;
            #pragma unroll
            for (int n = 0; n < D_STATE; ++n) {
                ea *= e1;
                h[n] = fmaf(h[n], ea, dtx * Bv[n]);
                yy = fmaf(h[n], Cv[n], yy);
            }
            float zv = bf2f(z_p[(size_t)t * (2 * D_INNER)]);
            float sig = 1.0f / (1.0f + __expf(-zv));
            y_p[(size_t)t * D_INNER] = f2bf((yy + xv * Dd) * (zv * sig));
        }
    } else {
        for (int t = 0; t < CHUNK; ++t) {
            float dt = dt_p[(size_t)t * D_INNER];
            float xv = bf2f(x_p[(size_t)t * D_INNER]);
            const float4* B4 = (const float4*)(Brow + (size_t)t * DBL_N);
            float4 b0 = B4[0], b1 = B4[1], b2 = B4[2], b3 = B4[3];
            float4 c0 = B4[4], c1 = B4[5], c2 = B4[6], c3 = B4[7];
            float Bv[16] = {b0.x,b0.y,b0.z,b0.w, b1.x,b1.y,b1.z,b1.w,
                            b2.x,b2.y,b2.z,b2.w, b3.x,b3.y,b3.z,b3.w};
            float Cv[16] = {c0.x,c0.y,c0.z,c0.w, c1.x,c1.y,c1.z,c1.w,
                            c2.x,c2.y,c2.z,c2.w, c3.x,c3.y,c3.z,c3.w};
            float dtx = dt * xv;
            float yy = 0.f;
            #pragma unroll
            for (int n = 0; n < D_STATE; ++n) {
                float ea = __expf(dt * An[n]);
                h[n] = fmaf(h[n], ea, dtx * Bv[n]);
                yy = fmaf(h[n], Cv[n], yy);
            }
            float zv = bf2f(z_p[(size_t)t * (2 * D_INNER)]);
            float sig = 1.0f / (1.0f + __expf(-zv));
            y_p[(size_t)t * D_INNER] = f2bf((yy + xv * Dd) * (zv * sig));
        }
    }
}

extern "C" void kernel_launch(void* const* d_in, const int* in_sizes, int n_in,
                              void* d_out, int out_size, void* d_ws, size_t ws_size,
                              hipStream_t stream) {
    const float* hs        = (const float*)d_in[0];
    const float* norm_w    = (const float*)d_in[1];
    const float* in_proj_w = (const float*)d_in[2];
    const float* conv_w    = (const float*)d_in[3];
    const float* conv_b    = (const float*)d_in[4];
    const float* x_proj_w  = (const float*)d_in[5];
    const float* dt_proj_w = (const float*)d_in[6];
    const float* dt_proj_b = (const float*)d_in[7];
    const float* A_log     = (const float*)d_in[8];
    const float* Dvec      = (const float*)d_in[9];
    const float* out_proj_w= (const float*)d_in[10];
    float* out = (float*)d_out;

    float* wsf      = (float*)d_ws;
    float* dbl      = wsf;                                //   393,216 f
    float* dbl_part = dbl      + (size_t)393216;          // 1,572,864 f
    float* dtb      = dbl_part + (size_t)1572864;         // 8,388,608 f
    float* sum_a    = dtb      + (size_t)8388608;         // 2,097,152 f
    float* sum_h    = sum_a    + (size_t)2097152;         // 2,097,152 f
    unsigned short* xz_bf    = (unsigned short*)(sum_h + 2097152); // 16,777,216 us
    unsigned short* xconv_bf = xz_bf    + (size_t)16777216;        //  8,388,608 us
    unsigned short* hnorm_bf = xconv_bf + (size_t)8388608;         //  4,194,304 us
    unsigned short* ybuf_bf  = hnorm_bf + (size_t)4194304;         //  8,388,608 us
    unsigned short* wi_bf    = ybuf_bf  + (size_t)8388608;         //  4,194,304 us
    unsigned short* wo_bf    = wi_bf    + (size_t)4194304;         //  2,097,152 us
    unsigned short* wx_bf    = wo_bf    + (size_t)2097152;         //    262,144 us (128-row pad)
    unsigned short* wdt_bf   = wx_bf    + (size_t)262144;          //    131,072 us
    unsigned short* dtr_bf   = wdt_bf   + (size_t)131072;          //    262,144 us

    // fused weight casts
    {
        int n0 = 2 * D_INNER * D_MODEL / 4;   // wi
        int n1 = D_MODEL * D_INNER / 4;       // wo
        int n2 = DBL_N * D_INNER / 4;         // wx
        int n3 = D_INNER * DT_RANK / 4;       // wdt
        int tot = n0 + n1 + n2 + n3;
        cast4_kernel<<<(tot + 255) / 256, 256, 0, stream>>>(
            (const float4*)in_proj_w,  (ushort4*)wi_bf,  n0,
            (const float4*)out_proj_w, (ushort4*)wo_bf,  n1,
            (const float4*)x_proj_w,   (ushort4*)wx_bf,  n2,
            (const float4*)dt_proj_w,  (ushort4*)wdt_bf, n3);
    }

    // 1. RMSNorm -> bf16
    rmsnorm_kernel<<<NTOK, 256, 0, stream>>>(hs, norm_w, hnorm_bf);
    // 2. in_proj (DIRECT MFMA, no LDS/no barriers): xz_bf = hnorm @ in_proj_w^T
    mfma_gemm_direct_kernel<<<dim3((2 * D_INNER) / 128, NTOK / 128), 256, 0, stream>>>(
        hnorm_bf, D_MODEL, wi_bf, D_MODEL, xz_bf, 2 * D_INNER, D_MODEL);
    // 3. depthwise causal conv + SiLU (bf16 in/out)
    conv_silu_kernel<<<(NTOK * D_INNER) / 256, 256, 0, stream>>>(
        xz_bf, conv_w, conv_b, xconv_bf);
    // 4. x_proj (MFMA, split-K x4): dbl_part[seg] = xconv @ x_proj_w^T (N=96)
    mfma_gemm_kernel<<<dim3(1, NTOK / 128, 4), 256, 0, stream>>>(
        xconv_bf, D_INNER, wx_bf, D_INNER, dbl_part, DBL_N, nullptr, 0,
        D_INNER / 4, DBL_N, nullptr, 0, (size_t)NTOK * DBL_N);
    reduce_xproj_kernel<<<(NTOK * DBL_N + 255) / 256, 256, 0, stream>>>(
        dbl_part, dbl, dtr_bf);
    // 5. dt_proj: dedicated 64x64-tile kernel (2048 blocks), bias + fast softplus
    dtproj_kernel<<<dim3(D_INNER / 64, NTOK / 64), 256, 0, stream>>>(
        dtr_bf, wdt_bf, dt_proj_b, dtb);
    // 6. scan: phase1 -> carry -> phase3
    scan_phase1_kernel<<<dim3(NCHUNK, D_INNER / 256, B_SZ), 256, 0, stream>>>(
        dtb, xconv_bf, dbl, A_log, sum_a, sum_h);
    scan_carry_kernel<<<(B_SZ * D_INNER * D_STATE) / 256, 256, 0, stream>>>(sum_a, sum_h);
    scan_phase3_kernel<<<dim3(NCHUNK, D_INNER / 256, B_SZ), 256, 0, stream>>>(
        dtb, xconv_bf, xz_bf, dbl, A_log, Dvec, sum_h, ybuf_bf);
    // 7. out_proj (MFMA) + residual -> d_out
    mfma_gemm_kernel<<<dim3(D_MODEL / 128, NTOK / 128), 256, 0, stream>>>(
        ybuf_bf, D_INNER, wo_bf, D_INNER, out, D_MODEL, nullptr, 0,
        D_INNER, D_MODEL, hs, D_MODEL, 0);
}

// Round 12
// 341.923 us; speedup vs baseline: 1.1858x; 1.1858x over previous
//
#include <hip/hip_runtime.h>
#include <math.h>

#define D_MODEL 1024
#define D_INNER 2048
#define D_STATE 16
#define D_CONV  4
#define DT_RANK 64
#define B_SZ    2
#define SEQ     2048
#define NTOK    (B_SZ*SEQ)            // 4096
#define DBL_N   (DT_RANK + 2*D_STATE) // 96
#define CHUNK   64
#define NCHUNK  (SEQ/CHUNK)           // 32

typedef __attribute__((ext_vector_type(8))) short short8;
typedef __attribute__((ext_vector_type(4))) float f32x4;

__device__ __forceinline__ unsigned short f2bf(float f) {
    union { float f; unsigned int u; } v; v.f = f;
    unsigned int r = v.u + 0x7fff + ((v.u >> 16) & 1);   // RNE
    return (unsigned short)(r >> 16);
}
__device__ __forceinline__ float bf2f(unsigned short u) {
    union { unsigned int u; float f; } v; v.u = ((unsigned int)u) << 16;
    return v.f;
}

// ---------------- RMSNorm: one block per token, bf16 output ----------------
__global__ __launch_bounds__(256) void rmsnorm_kernel(
    const float* __restrict__ h, const float* __restrict__ w, unsigned short* __restrict__ out)
{
    int tok = blockIdx.x;
    const float4* row = (const float4*)(h + (size_t)tok * D_MODEL);
    float4 v = row[threadIdx.x];
    float ss = v.x*v.x + v.y*v.y + v.z*v.z + v.w*v.w;
    #pragma unroll
    for (int off = 32; off >= 1; off >>= 1) ss += __shfl_down(ss, off, 64);
    __shared__ float red[4];
    int wave = threadIdx.x >> 6, lane = threadIdx.x & 63;
    if (lane == 0) red[wave] = ss;
    __syncthreads();
    float tot = red[0] + red[1] + red[2] + red[3];
    float scale = rsqrtf(tot * (1.0f / D_MODEL) + 1e-5f);
    float4 wv = ((const float4*)w)[threadIdx.x];
    ushort4 o;
    o.x = f2bf(v.x * scale * wv.x);
    o.y = f2bf(v.y * scale * wv.y);
    o.z = f2bf(v.z * scale * wv.z);
    o.w = f2bf(v.w * scale * wv.w);
    ((ushort4*)(out + (size_t)tok * D_MODEL))[threadIdx.x] = o;
}

// ---------------- fused fp32 -> bf16 cast for 4 weight matrices ----------------
__global__ __launch_bounds__(256) void cast4_kernel(
    const float4* __restrict__ s0, ushort4* __restrict__ d0, int n0,
    const float4* __restrict__ s1, ushort4* __restrict__ d1, int n1,
    const float4* __restrict__ s2, ushort4* __restrict__ d2, int n2,
    const float4* __restrict__ s3, ushort4* __restrict__ d3, int n3)
{
    int i = blockIdx.x * 256 + threadIdx.x;
    const float4* s; ushort4* d;
    if (i < n0) { s = s0; d = d0; }
    else if ((i -= n0) < n1) { s = s1; d = d1; }
    else if ((i -= n1) < n2) { s = s2; d = d2; }
    else if ((i -= n2) < n3) { s = s3; d = d3; }
    else return;
    float4 v = s[i];
    ushort4 o; o.x = f2bf(v.x); o.y = f2bf(v.y); o.z = f2bf(v.z); o.w = f2bf(v.w);
    d[i] = o;
}

// ---------------- bf16 MFMA GEMM (128x128, LDS), transposed accumulator ----------------
// R9 configuration: linear global_load_lds staging, quad*8 reads (benign 2-cyc
// conflicts), packed stores. This is the measured plateau for these shapes.
__global__ __launch_bounds__(256) void mfma_gemm_kernel(
    const unsigned short* __restrict__ A, int lda,
    const unsigned short* __restrict__ W, int ldw,
    float* __restrict__ C, int ldc,
    unsigned short* __restrict__ Cbf, int ldcbf,
    int kLen, int Nmax,
    const float* __restrict__ add, int ldadd,
    size_t segStride)
{
    __shared__ __align__(16) unsigned short As[128 * 32];
    __shared__ __align__(16) unsigned short Bs[128 * 32];
    const int bm = blockIdx.y * 128;
    const int bn = blockIdx.x * 128;
    const int kBeg = blockIdx.z * kLen;
    const int tid = threadIdx.x;
    const int lane = tid & 63;
    const int wave = tid >> 6;
    const int wm = (wave >> 1) * 64;
    const int wn = (wave & 1) * 64;
    const int frow = lane & 15;
    const int quad = lane >> 4;

    if (C) C += blockIdx.z * segStride;

    f32x4 acc[4][4];
    #pragma unroll
    for (int i = 0; i < 4; ++i)
        #pragma unroll
        for (int j = 0; j < 4; ++j)
            acc[i][j] = (f32x4){0.f, 0.f, 0.f, 0.f};

    for (int k0 = kBeg; k0 < kBeg + kLen; k0 += 32) {
        __syncthreads();
        #pragma unroll
        for (int i = 0; i < 2; ++i) {
            int q = (wave * 2 + i) * 64 + lane;
            int r = q >> 2, cl = q & 3;
            const unsigned short* ga = A + (size_t)(bm + r) * lda + k0 + cl * 8;
            const unsigned short* gb = W + (size_t)(bn + r) * ldw + k0 + cl * 8;
            __builtin_amdgcn_global_load_lds(
                (const __attribute__((address_space(1))) void*)ga,
                (__attribute__((address_space(3))) void*)(As + (wave * 2 + i) * 512),
                16, 0, 0);
            __builtin_amdgcn_global_load_lds(
                (const __attribute__((address_space(1))) void*)gb,
                (__attribute__((address_space(3))) void*)(Bs + (wave * 2 + i) * 512),
                16, 0, 0);
        }
        __syncthreads();
        short8 af[4], bf[4];
        #pragma unroll
        for (int i = 0; i < 4; ++i)
            af[i] = *(const short8*)&As[(wm + i * 16 + frow) * 32 + quad * 8];
        #pragma unroll
        for (int j = 0; j < 4; ++j)
            bf[j] = *(const short8*)&Bs[(wn + j * 16 + frow) * 32 + quad * 8];
        #pragma unroll
        for (int i = 0; i < 4; ++i)
            #pragma unroll
            for (int j = 0; j < 4; ++j)
                acc[i][j] = __builtin_amdgcn_mfma_f32_16x16x32_bf16(
                    bf[j], af[i], acc[i][j], 0, 0, 0);
    }

    #pragma unroll
    for (int i = 0; i < 4; ++i) {
        int row = bm + wm + i * 16 + frow;
        #pragma unroll
        for (int j = 0; j < 4; ++j) {
            int col = bn + wn + j * 16 + quad * 4;
            if (col < Nmax) {
                f32x4 v = acc[i][j];
                if (add) {
                    float4 av = *(const float4*)&add[(size_t)row * ldadd + col];
                    v[0] += av.x; v[1] += av.y; v[2] += av.z; v[3] += av.w;
                }
                if (C) {
                    float4 o = {v[0], v[1], v[2], v[3]};
                    *(float4*)&C[(size_t)row * ldc + col] = o;
                }
                if (Cbf) {
                    ushort4 o = {f2bf(v[0]), f2bf(v[1]), f2bf(v[2]), f2bf(v[3])};
                    *(ushort4*)&Cbf[(size_t)row * ldcbf + col] = o;
                }
            }
        }
    }
}

// ---------------- dt_proj: 64x64-tile MFMA + bias + fast softplus -> bf16 ----------------
__global__ __launch_bounds__(256) void dtproj_kernel(
    const unsigned short* __restrict__ A,
    const unsigned short* __restrict__ W,
    const float* __restrict__ bias,
    unsigned short* __restrict__ Cbf)
{
    __shared__ __align__(16) unsigned short As[64 * 32];
    __shared__ __align__(16) unsigned short Bs[64 * 32];
    const int bm = blockIdx.y * 64;
    const int bn = blockIdx.x * 64;
    const int tid = threadIdx.x;
    const int lane = tid & 63;
    const int wave = tid >> 6;
    const int frow = lane & 15;
    const int quad = lane >> 4;

    f32x4 acc[4];
    #pragma unroll
    for (int i = 0; i < 4; ++i) acc[i] = (f32x4){0.f, 0.f, 0.f, 0.f};

    #pragma unroll
    for (int k0 = 0; k0 < DT_RANK; k0 += 32) {
        __syncthreads();
        {
            int r = tid >> 2, cl = tid & 3;
            const unsigned short* ga = A + (size_t)(bm + r) * DT_RANK + k0 + cl * 8;
            const unsigned short* gb = W + (size_t)(bn + r) * DT_RANK + k0 + cl * 8;
            __builtin_amdgcn_global_load_lds(
                (const __attribute__((address_space(1))) void*)ga,
                (__attribute__((address_space(3))) void*)(As + wave * 512),
                16, 0, 0);
            __builtin_amdgcn_global_load_lds(
                (const __attribute__((address_space(1))) void*)gb,
                (__attribute__((address_space(3))) void*)(Bs + wave * 512),
                16, 0, 0);
        }
        __syncthreads();
        short8 bf = *(const short8*)&Bs[(wave * 16 + frow) * 32 + quad * 8];
        #pragma unroll
        for (int i = 0; i < 4; ++i) {
            short8 af = *(const short8*)&As[(i * 16 + frow) * 32 + quad * 8];
            acc[i] = __builtin_amdgcn_mfma_f32_16x16x32_bf16(bf, af, acc[i], 0, 0, 0);
        }
    }

    const int col = bn + wave * 16 + quad * 4;
    float4 bv = *(const float4*)&bias[col];
    #pragma unroll
    for (int i = 0; i < 4; ++i) {
        int row = bm + i * 16 + frow;
        f32x4 v = acc[i];
        v[0] += bv.x; v[1] += bv.y; v[2] += bv.z; v[3] += bv.w;
        #pragma unroll
        for (int r = 0; r < 4; ++r)
            v[r] = (v[r] > 15.0f) ? v[r] : __logf(1.0f + __expf(v[r]));
        ushort4 o = {f2bf(v[0]), f2bf(v[1]), f2bf(v[2]), f2bf(v[3])};
        *(ushort4*)&Cbf[(size_t)row * D_INNER + col] = o;
    }
}

// ---------------- x_proj split-K reduce + dt_r bf16 extract ----------------
__global__ __launch_bounds__(256) void reduce_xproj_kernel(
    const float* __restrict__ part, float* __restrict__ dbl,
    unsigned short* __restrict__ dtr)
{
    const int N = NTOK * DBL_N;
    int idx = blockIdx.x * 256 + threadIdx.x;
    if (idx >= N) return;
    float s = part[idx] + part[idx + N] + part[idx + 2 * N] + part[idx + 3 * N];
    dbl[idx] = s;
    unsigned int col = (unsigned int)idx % DBL_N;
    if (col < DT_RANK) {
        unsigned int tok = (unsigned int)idx / DBL_N;
        dtr[(size_t)tok * DT_RANK + col] = f2bf(s);
    }
}

// ---------------- Causal depthwise conv (k=4) + SiLU, 4 d/thread, bf16 ----------------
__global__ __launch_bounds__(256) void conv_silu_kernel(
    const unsigned short* __restrict__ xz, const float* __restrict__ cw,
    const float* __restrict__ cb, unsigned short* __restrict__ out_bf)
{
    int idx = blockIdx.x * 256 + threadIdx.x;   // over NTOK*D_INNER/4
    int d4 = (idx << 2) & (D_INNER - 1);        // d base, multiple of 4
    int t = (idx >> 9) & (SEQ - 1);
    int b = idx >> 20;
    const unsigned short* xcol = xz + (size_t)b * SEQ * (2 * D_INNER) + d4;
    ushort4 zz = {0, 0, 0, 0};
    ushort4 x0 = (t >= 3) ? *(const ushort4*)(xcol + (size_t)(t - 3) * (2 * D_INNER)) : zz;
    ushort4 x1 = (t >= 2) ? *(const ushort4*)(xcol + (size_t)(t - 2) * (2 * D_INNER)) : zz;
    ushort4 x2 = (t >= 1) ? *(const ushort4*)(xcol + (size_t)(t - 1) * (2 * D_INNER)) : zz;
    ushort4 x3 = *(const ushort4*)(xcol + (size_t)t * (2 * D_INNER));
    const float4* cw4 = (const float4*)cw;      // cw4[d] = taps of channel d
    float4 cbv = *(const float4*)&cb[d4];
    float accv[4];
    {
        float4 q = cw4[d4 + 0];
        accv[0] = cbv.x + bf2f(x0.x)*q.x + bf2f(x1.x)*q.y + bf2f(x2.x)*q.z + bf2f(x3.x)*q.w;
    }
    {
        float4 q = cw4[d4 + 1];
        accv[1] = cbv.y + bf2f(x0.y)*q.x + bf2f(x1.y)*q.y + bf2f(x2.y)*q.z + bf2f(x3.y)*q.w;
    }
    {
        float4 q = cw4[d4 + 2];
        accv[2] = cbv.z + bf2f(x0.z)*q.x + bf2f(x1.z)*q.y + bf2f(x2.z)*q.z + bf2f(x3.z)*q.w;
    }
    {
        float4 q = cw4[d4 + 3];
        accv[3] = cbv.w + bf2f(x0.w)*q.x + bf2f(x1.w)*q.y + bf2f(x2.w)*q.z + bf2f(x3.w)*q.w;
    }
    ushort4 o;
    o.x = f2bf(accv[0] / (1.0f + __expf(-accv[0])));
    o.y = f2bf(accv[1] / (1.0f + __expf(-accv[1])));
    o.z = f2bf(accv[2] / (1.0f + __expf(-accv[2])));
    o.w = f2bf(accv[3] / (1.0f + __expf(-accv[3])));
    *(ushort4*)&out_bf[(size_t)(b * SEQ + t) * D_INNER + d4] = o;
}

// ---------------- Scan phase 1: per-chunk summaries, one thread per d ----------------
__global__ __launch_bounds__(256) void scan_phase1_kernel(
    const unsigned short* __restrict__ dtb, const unsigned short* __restrict__ xconv,
    const float* __restrict__ dbl, const float* __restrict__ A_log,
    float* __restrict__ sum_a, float* __restrict__ sum_h)
{
    const int d = blockIdx.y * 256 + threadIdx.x;
    const int c = blockIdx.x;
    const int b = blockIdx.z;
    const int t0 = c * CHUNK;

    float An[D_STATE];
    bool fast = true;
    #pragma unroll
    for (int n = 0; n < D_STATE; ++n) {
        An[n] = -__expf(A_log[d * D_STATE + n]);
        fast = fast && (fabsf(An[n] + (float)(n + 1)) < 2e-3f);
    }
    const unsigned short* dt_p = dtb + ((size_t)b * SEQ + t0) * D_INNER + d;
    const unsigned short* x_p = xconv + ((size_t)b * SEQ + t0) * D_INNER + d;
    const float* Brow = dbl + ((size_t)b * SEQ + t0) * DBL_N + DT_RANK;   // wave-uniform

    float h[D_STATE];
    #pragma unroll
    for (int n = 0; n < D_STATE; ++n) h[n] = 0.f;
    float sumdt = 0.f;

    if (fast) {
        for (int t = 0; t < CHUNK; ++t) {
            float dt = bf2f(dt_p[(size_t)t * D_INNER]);
            float xv = bf2f(x_p[(size_t)t * D_INNER]);
            const float4* B4 = (const float4*)(Brow + (size_t)t * DBL_N);
            float4 b0 = B4[0], b1 = B4[1], b2 = B4[2], b3 = B4[3];
            float Bv[16] = {b0.x,b0.y,b0.z,b0.w, b1.x,b1.y,b1.z,b1.w,
                            b2.x,b2.y,b2.z,b2.w, b3.x,b3.y,b3.z,b3.w};
            sumdt += dt;
            float e1 = __expf(-dt);
            float dtx = dt * xv;
            float ea = 1.f;
            #pragma unroll
            for (int n = 0; n < D_STATE; ++n) {
                ea *= e1;
                h[n] = fmaf(h[n], ea, dtx * Bv[n]);
            }
        }
    } else {
        for (int t = 0; t < CHUNK; ++t) {
            float dt = bf2f(dt_p[(size_t)t * D_INNER]);
            float xv = bf2f(x_p[(size_t)t * D_INNER]);
            const float4* B4 = (const float4*)(Brow + (size_t)t * DBL_N);
            float4 b0 = B4[0], b1 = B4[1], b2 = B4[2], b3 = B4[3];
            float Bv[16] = {b0.x,b0.y,b0.z,b0.w, b1.x,b1.y,b1.z,b1.w,
                            b2.x,b2.y,b2.z,b2.w, b3.x,b3.y,b3.z,b3.w};
            sumdt += dt;
            float dtx = dt * xv;
            #pragma unroll
            for (int n = 0; n < D_STATE; ++n) {
                float ea = __expf(dt * An[n]);
                h[n] = fmaf(h[n], ea, dtx * Bv[n]);
            }
        }
    }

    float a[D_STATE];
    if (fast) {
        float E = __expf(-sumdt);
        float ea = 1.f;
        #pragma unroll
        for (int n = 0; n < D_STATE; ++n) { ea *= E; a[n] = ea; }
    } else {
        #pragma unroll
        for (int n = 0; n < D_STATE; ++n) a[n] = __expf(An[n] * sumdt);
    }
    size_t base = (((size_t)b * D_INNER + d) * NCHUNK + c) * D_STATE;
    #pragma unroll
    for (int i = 0; i < 4; ++i) {
        ((float4*)(sum_a + base))[i] = (float4){a[4*i], a[4*i+1], a[4*i+2], a[4*i+3]};
        ((float4*)(sum_h + base))[i] = (float4){h[4*i], h[4*i+1], h[4*i+2], h[4*i+3]};
    }
}

// ---------------- Scan phase 2: inter-chunk carry (in-place over sum_h) ----------------
__global__ __launch_bounds__(256) void scan_carry_kernel(
    const float* __restrict__ sum_a, float* __restrict__ sum_h)
{
    size_t g = (size_t)blockIdx.x * 256 + threadIdx.x;   // (b,d,n): 65536 groups
    size_t bd = g >> 4;
    int n = (int)(g & 15);
    size_t base = bd * NCHUNK * D_STATE + n;
    float hh = 0.f;
    for (int c = 0; c < NCHUNK; ++c) {
        size_t idx = base + (size_t)c * D_STATE;
        float a = sum_a[idx];
        float hp = sum_h[idx];
        sum_h[idx] = hh;
        hh = fmaf(hh, a, hp);
    }
}

// ---------------- Scan phase 3: re-scan with carry, emit y (bf16) ----------------
__global__ __launch_bounds__(256) void scan_phase3_kernel(
    const unsigned short* __restrict__ dtb, const unsigned short* __restrict__ xconv,
    const unsigned short* __restrict__ xz, const float* __restrict__ dbl,
    const float* __restrict__ A_log, const float* __restrict__ Dvec,
    const float* __restrict__ hinit, unsigned short* __restrict__ y)
{
    const int d = blockIdx.y * 256 + threadIdx.x;
    const int c = blockIdx.x;
    const int b = blockIdx.z;
    const int t0 = c * CHUNK;

    float An[D_STATE];
    bool fast = true;
    #pragma unroll
    for (int n = 0; n < D_STATE; ++n) {
        An[n] = -__expf(A_log[d * D_STATE + n]);
        fast = fast && (fabsf(An[n] + (float)(n + 1)) < 2e-3f);
    }
    const float Dd = Dvec[d];
    const unsigned short* dt_p = dtb + ((size_t)b * SEQ + t0) * D_INNER + d;
    const unsigned short* x_p = xconv + ((size_t)b * SEQ + t0) * D_INNER + d;
    const unsigned short* z_p = xz + ((size_t)b * SEQ + t0) * (2 * D_INNER) + D_INNER + d;
    const float* Brow = dbl + ((size_t)b * SEQ + t0) * DBL_N + DT_RANK;
    unsigned short* y_p = y + ((size_t)b * SEQ + t0) * D_INNER + d;

    size_t base = (((size_t)b * D_INNER + d) * NCHUNK + c) * D_STATE;
    float h[D_STATE];
    #pragma unroll
    for (int i = 0; i < 4; ++i) {
        float4 hv = ((const float4*)(hinit + base))[i];
        h[4*i] = hv.x; h[4*i+1] = hv.y; h[4*i+2] = hv.z; h[4*i+3] = hv.w;
    }

    if (fast) {
        for (int t = 0; t < CHUNK; ++t) {
            float dt = bf2f(dt_p[(size_t)t * D_INNER]);
            float xv = bf2f(x_p[(size_t)t * D_INNER]);
            const float4* B4 = (const float4*)(Brow + (size_t)t * DBL_N);
            float4 b0 = B4[0], b1 = B4[1], b2 = B4[2], b3 = B4[3];
            float4 c0 = B4[4], c1 = B4[5], c2 = B4[6], c3 = B4[7];
            float Bv[16] = {b0.x,b0.y,b0.z,b0.w, b1.x,b1.y,b1.z,b1.w,
                            b2.x,b2.y,b2.z,b2.w, b3.x,b3.y,b3.z,b3.w};
            float Cv[16] = {c0.x,c0.y,c0.z,c0.w, c1.x,c1.y,c1.z,c1.w,
                            c2.x,c2.y,c2.z,c2.w, c3.x,c3.y,c3.z,c3.w};
            float e1 = __expf(-dt);
            float dtx = dt * xv;
            float ea = 1.f, yy = 0.f;
            #pragma unroll
            for (int n = 0; n < D_STATE; ++n) {
                ea *= e1;
                h[n] = fmaf(h[n], ea, dtx * Bv[n]);
                yy = fmaf(h[n], Cv[n], yy);
            }
            float zv = bf2f(z_p[(size_t)t * (2 * D_INNER)]);
            float sig = 1.0f / (1.0f + __expf(-zv));
            y_p[(size_t)t * D_INNER] = f2bf((yy + xv * Dd) * (zv * sig));
        }
    } else {
        for (int t = 0; t < CHUNK; ++t) {
            float dt = bf2f(dt_p[(size_t)t * D_INNER]);
            float xv = bf2f(x_p[(size_t)t * D_INNER]);
            const float4* B4 = (const float4*)(Brow + (size_t)t * DBL_N);
            float4 b0 = B4[0], b1 = B4[1], b2 = B4[2], b3 = B4[3];
            float4 c0 = B4[4], c1 = B4[5], c2 = B4[6], c3 = B4[7];
            float Bv[16] = {b0.x,b0.y,b0.z,b0.w, b1.x,b1.y,b1.z,b1.w,
                            b2.x,b2.y,b2.z,b2.w, b3.x,b3.y,b3.z,b3.w};
            float Cv[16] = {c0.x,c0.y,c0.z,c0.w, c1.x,c1.y,c1.z,c1.w,
                            c2.x,c2.y,c2.z,c2.w, c3.x,c3.y,c3.z,c3.w};
            float dtx = dt * xv;
            float yy = 0.f;
            #pragma unroll
            for (int n = 0; n < D_STATE; ++n) {
                float ea = __expf(dt * An[n]);
                h[n] = fmaf(h[n], ea, dtx * Bv[n]);
                yy = fmaf(h[n], Cv[n], yy);
            }
            float zv = bf2f(z_p[(size_t)t * (2 * D_INNER)]);
            float sig = 1.0f / (1.0f + __expf(-zv));
            y_p[(size_t)t * D_INNER] = f2bf((yy + xv * Dd) * (zv * sig));
        }
    }
}

extern "C" void kernel_launch(void* const* d_in, const int* in_sizes, int n_in,
                              void* d_out, int out_size, void* d_ws, size_t ws_size,
                              hipStream_t stream) {
    const float* hs        = (const float*)d_in[0];
    const float* norm_w    = (const float*)d_in[1];
    const float* in_proj_w = (const float*)d_in[2];
    const float* conv_w    = (const float*)d_in[3];
    const float* conv_b    = (const float*)d_in[4];
    const float* x_proj_w  = (const float*)d_in[5];
    const float* dt_proj_w = (const float*)d_in[6];
    const float* dt_proj_b = (const float*)d_in[7];
    const float* A_log     = (const float*)d_in[8];
    const float* Dvec      = (const float*)d_in[9];
    const float* out_proj_w= (const float*)d_in[10];
    float* out = (float*)d_out;

    float* wsf      = (float*)d_ws;
    float* dbl      = wsf;                                //   393,216 f
    float* dbl_part = dbl      + (size_t)393216;          // 1,572,864 f
    float* sum_a    = dbl_part + (size_t)1572864;         // 2,097,152 f
    float* sum_h    = sum_a    + (size_t)2097152;         // 2,097,152 f
    unsigned short* dtb_bf   = (unsigned short*)(sum_h + 2097152); //  8,388,608 us
    unsigned short* xz_bf    = dtb_bf   + (size_t)8388608;         // 16,777,216 us
    unsigned short* xconv_bf = xz_bf    + (size_t)16777216;        //  8,388,608 us
    unsigned short* hnorm_bf = xconv_bf + (size_t)8388608;         //  4,194,304 us
    unsigned short* ybuf_bf  = hnorm_bf + (size_t)4194304;         //  8,388,608 us
    unsigned short* wi_bf    = ybuf_bf  + (size_t)8388608;         //  4,194,304 us
    unsigned short* wo_bf    = wi_bf    + (size_t)4194304;         //  2,097,152 us
    unsigned short* wx_bf    = wo_bf    + (size_t)2097152;         //    262,144 us (128-row pad)
    unsigned short* wdt_bf   = wx_bf    + (size_t)262144;          //    131,072 us
    unsigned short* dtr_bf   = wdt_bf   + (size_t)131072;          //    262,144 us

    // fused weight casts
    {
        int n0 = 2 * D_INNER * D_MODEL / 4;   // wi
        int n1 = D_MODEL * D_INNER / 4;       // wo
        int n2 = DBL_N * D_INNER / 4;         // wx
        int n3 = D_INNER * DT_RANK / 4;       // wdt
        int tot = n0 + n1 + n2 + n3;
        cast4_kernel<<<(tot + 255) / 256, 256, 0, stream>>>(
            (const float4*)in_proj_w,  (ushort4*)wi_bf,  n0,
            (const float4*)out_proj_w, (ushort4*)wo_bf,  n1,
            (const float4*)x_proj_w,   (ushort4*)wx_bf,  n2,
            (const float4*)dt_proj_w,  (ushort4*)wdt_bf, n3);
    }

    // 1. RMSNorm -> bf16
    rmsnorm_kernel<<<NTOK, 256, 0, stream>>>(hs, norm_w, hnorm_bf);
    // 2. in_proj (MFMA 128x128, R9 config): xz_bf = hnorm @ in_proj_w^T
    mfma_gemm_kernel<<<dim3((2 * D_INNER) / 128, NTOK / 128), 256, 0, stream>>>(
        hnorm_bf, D_MODEL, wi_bf, D_MODEL, nullptr, 0, xz_bf, 2 * D_INNER,
        D_MODEL, 2 * D_INNER, nullptr, 0, 0);
    // 3. depthwise causal conv + SiLU (bf16, 4 d/thread vectorized)
    conv_silu_kernel<<<(NTOK * D_INNER / 4) / 256, 256, 0, stream>>>(
        xz_bf, conv_w, conv_b, xconv_bf);
    // 4. x_proj (MFMA, split-K x4): dbl_part[seg] = xconv @ x_proj_w^T (N=96)
    mfma_gemm_kernel<<<dim3(1, NTOK / 128, 4), 256, 0, stream>>>(
        xconv_bf, D_INNER, wx_bf, D_INNER, dbl_part, DBL_N, nullptr, 0,
        D_INNER / 4, DBL_N, nullptr, 0, (size_t)NTOK * DBL_N);
    reduce_xproj_kernel<<<(NTOK * DBL_N + 255) / 256, 256, 0, stream>>>(
        dbl_part, dbl, dtr_bf);
    // 5. dt_proj: 64x64 tiles, bias + fast softplus -> bf16
    dtproj_kernel<<<dim3(D_INNER / 64, NTOK / 64), 256, 0, stream>>>(
        dtr_bf, wdt_bf, dt_proj_b, dtb_bf);
    // 6. scan: phase1 -> carry -> phase3
    scan_phase1_kernel<<<dim3(NCHUNK, D_INNER / 256, B_SZ), 256, 0, stream>>>(
        dtb_bf, xconv_bf, dbl, A_log, sum_a, sum_h);
    scan_carry_kernel<<<(B_SZ * D_INNER * D_STATE) / 256, 256, 0, stream>>>(sum_a, sum_h);
    scan_phase3_kernel<<<dim3(NCHUNK, D_INNER / 256, B_SZ), 256, 0, stream>>>(
        dtb_bf, xconv_bf, xz_bf, dbl, A_log, Dvec, sum_h, ybuf_bf);
    // 7. out_proj (MFMA) + residual -> d_out
    mfma_gemm_kernel<<<dim3(D_MODEL / 128, NTOK / 128), 256, 0, stream>>>(
        ybuf_bf, D_INNER, wo_bf, D_INNER, out, D_MODEL, nullptr, 0,
        D_INNER, D_MODEL, hs, D_MODEL, 0);
}